// Round 4
// baseline (1210.081 us; speedup 1.0000x reference)
//
#include <hip/hip_runtime.h>
#include <hip/hip_bf16.h>
#include <math.h>

#define NN 50000
#define NE 1600000
#define NG 256
#define DIN 128
#define D1 100
#define D1P 104      // bf16 row stride for y1
#define D2 20
#define D2P 24       // bf16 row stride for y2 (48 B)
#define DSELF 64
#define P 8          // XCD partitions
#define PN (P * NN)  // 400000

static __device__ __forceinline__ unsigned short f2bf(float x) {
    __hip_bfloat16 h = __float2bfloat16(x);
    unsigned short u;
    __builtin_memcpy(&u, &h, 2);
    return u;
}
static __device__ __forceinline__ float bflo(unsigned u) {
    union { unsigned i; float f; } c; c.i = u << 16; return c.f;
}
static __device__ __forceinline__ float bfhi(unsigned u) {
    union { unsigned i; float f; } c; c.i = u & 0xffff0000u; return c.f;
}

// ---------------- K1: degree count (XCD-partitioned) + graph_start marks ----------------
// blocks [0,1563): deg.  blocks [1563,1759): mark.
#define DEG_BLOCKS 1563
__global__ __launch_bounds__(256) void k_deg_mark(const int* __restrict__ dst,
        int* __restrict__ deg, const int* __restrict__ gid, int* __restrict__ graph_start) {
    int b = blockIdx.x;
    if (b < DEG_BLOCKS) {
        int e0 = (b * 256 + threadIdx.x) * 4;
        if (e0 < NE) {
            int4 d = *reinterpret_cast<const int4*>(dst + e0);
            int off = (b & 7) * NN;
            atomicAdd(&deg[off + d.x], 1);
            atomicAdd(&deg[off + d.y], 1);
            atomicAdd(&deg[off + d.z], 1);
            atomicAdd(&deg[off + d.w], 1);
        }
    } else {
        int i = (b - DEG_BLOCKS) * 256 + threadIdx.x;
        if (i >= NN) return;
        int g = gid[i];
        if (i == 0) {
            for (int x = 0; x <= g; x++) graph_start[x] = 0;
        } else {
            int p = gid[i - 1];
            if (p != g) for (int x = p + 1; x <= g; x++) graph_start[x] = i;
        }
        if (i == NN - 1) for (int x = g + 1; x <= NG; x++) graph_start[x] = NN;
    }
}

// ---------------- K2: exclusive scan over deg[0..PN) -> row_start[0..PN] ----------------
#define SCAN_T 1024
#define CHUNK 391   // 1024*391 = 400384 >= 400000
__global__ __launch_bounds__(1024) void k_scan(const int* __restrict__ deg,
                                               int* __restrict__ row_start) {
    __shared__ int psum[SCAN_T];
    int tid = threadIdx.x;
    int start = tid * CHUNK;
    int s = 0;
    for (int i = 0; i < CHUNK; i++) {
        int idx = start + i;
        s += (idx < PN) ? deg[idx] : 0;
    }
    psum[tid] = s;
    __syncthreads();
    for (int off = 1; off < SCAN_T; off <<= 1) {
        int t = (tid >= off) ? psum[tid - off] : 0;
        __syncthreads();
        psum[tid] += t;
        __syncthreads();
    }
    int run = (tid > 0) ? psum[tid - 1] : 0;
    for (int i = 0; i < CHUNK; i++) {
        int idx = start + i;
        if (idx < PN) { row_start[idx] = run; run += deg[idx]; }
    }
    if (tid == SCAN_T - 1) row_start[PN] = psum[SCAN_T - 1];
}

// ---------------- K3: CSR fill (XCD-partitioned: blockIdx%8 owns partition) ----------------
__global__ __launch_bounds__(256) void k_fill(const int* __restrict__ src,
        const int* __restrict__ dst, const int* __restrict__ row_start,
        int* __restrict__ cursor, int* __restrict__ csr) {
    int b = blockIdx.x;
    int e0 = (b * 256 + threadIdx.x) * 4;
    if (e0 >= NE) return;
    int4 d = *reinterpret_cast<const int4*>(dst + e0);
    int4 sv = *reinterpret_cast<const int4*>(src + e0);
    int off = (b & 7) * NN;
    {
        int pd = off + d.x; int slot = atomicAdd(&cursor[pd], 1);
        csr[row_start[pd] + slot] = sv.x;
    }
    {
        int pd = off + d.y; int slot = atomicAdd(&cursor[pd], 1);
        csr[row_start[pd] + slot] = sv.y;
    }
    {
        int pd = off + d.z; int slot = atomicAdd(&cursor[pd], 1);
        csr[row_start[pd] + slot] = sv.z;
    }
    {
        int pd = off + d.w; int slot = atomicAdd(&cursor[pd], 1);
        csr[row_start[pd] + slot] = sv.w;
    }
}

// ---------------- K4: gemm1: y1 = feat @ W1 (bf16 out), W1 bf16 + feat tile in LDS ----------
// 1250 blocks x 40 rows; 250 active threads: cg = tid%25 (4 cols), rg = tid/25 (4 rows)
__global__ __launch_bounds__(256) void k_gemm1(const float* __restrict__ feat,
        const float* __restrict__ W1, unsigned short* __restrict__ y1) {
    __shared__ unsigned short W1s[DIN * D1];   // 25.6 KB bf16 [k][100]
    __shared__ float feats[40 * DIN];          // 20.5 KB
    int tid = threadIdx.x;
    int n0 = blockIdx.x * 40;
    // stage W1 -> bf16: 6400 float2
    for (int i = 0; i < 25; i++) {
        int f2 = tid + 256 * i;   // < 6400
        float2 w = *reinterpret_cast<const float2*>(W1 + f2 * 2);
        unsigned pack = (unsigned)f2bf(w.x) | ((unsigned)f2bf(w.y) << 16);
        *reinterpret_cast<unsigned*>(W1s + f2 * 2) = pack;
    }
    // stage feat tile: 40*32 float4 = 1280
    for (int i = 0; i < 5; i++) {
        int f4 = tid + 256 * i;   // < 1280
        *reinterpret_cast<float4*>(feats + f4 * 4) =
            *reinterpret_cast<const float4*>(feat + (size_t)n0 * DIN + f4 * 4);
    }
    __syncthreads();
    if (tid >= 250) return;
    int cg = tid % 25, rg = tid / 25;
    float acc[4][4];
#pragma unroll
    for (int i = 0; i < 4; i++)
#pragma unroll
        for (int j = 0; j < 4; j++) acc[i][j] = 0.f;
    const float* f0 = feats + (rg * 4 + 0) * DIN;
    const float* f1 = feats + (rg * 4 + 1) * DIN;
    const float* f2 = feats + (rg * 4 + 2) * DIN;
    const float* f3 = feats + (rg * 4 + 3) * DIN;
#pragma unroll 4
    for (int k = 0; k < DIN; k++) {
        ushort4 wp = *reinterpret_cast<const ushort4*>(W1s + k * D1 + cg * 4);
        float w0 = bflo(wp.x), w1 = bflo(wp.y), w2 = bflo(wp.z), w3 = bflo(wp.w);
        float a0 = f0[k], a1 = f1[k], a2 = f2[k], a3 = f3[k];
        acc[0][0] += a0 * w0; acc[0][1] += a0 * w1; acc[0][2] += a0 * w2; acc[0][3] += a0 * w3;
        acc[1][0] += a1 * w0; acc[1][1] += a1 * w1; acc[1][2] += a1 * w2; acc[1][3] += a1 * w3;
        acc[2][0] += a2 * w0; acc[2][1] += a2 * w1; acc[2][2] += a2 * w2; acc[2][3] += a2 * w3;
        acc[3][0] += a3 * w0; acc[3][1] += a3 * w1; acc[3][2] += a3 * w2; acc[3][3] += a3 * w3;
    }
#pragma unroll
    for (int i = 0; i < 4; i++) {
        int n = n0 + rg * 4 + i;
        ushort4 st;
        st.x = f2bf(acc[i][0]); st.y = f2bf(acc[i][1]);
        st.z = f2bf(acc[i][2]); st.w = f2bf(acc[i][3]);
        *reinterpret_cast<ushort4*>(y1 + (size_t)n * D1P + cg * 4) = st;
        if (cg == 24) {
            ushort4 z; z.x = z.y = z.z = z.w = 0;
            *reinterpret_cast<ushort4*>(y1 + (size_t)n * D1P + 100) = z;
        }
    }
}

// ---------------- K5: agg1 (mean over 8 csr partitions) + fused gemm2 -> y2 bf16 --------
__global__ __launch_bounds__(256) void k_agg1g2(const unsigned short* __restrict__ y1,
        const int* __restrict__ csr, const int* __restrict__ row_start,
        const float* __restrict__ b1, const float* __restrict__ W2,
        unsigned short* __restrict__ y2b) {
    __shared__ float W2s[D1 * D2];   // 8 KB
    __shared__ float h1s[4][D1P];
    int tid = threadIdx.x;
    // stage W2: 500 float4
    for (int i = 0; i < 2; i++) {
        int f4 = tid + 256 * i;
        if (f4 < 500)
            *reinterpret_cast<float4*>(W2s + f4 * 4) =
                *reinterpret_cast<const float4*>(W2 + f4 * 4);
    }
    int w = tid >> 6;
    int n = blockIdx.x * 4 + w;
    int lane = tid & 63;
    int esub = lane >> 4;   // 0..3
    int dg = lane & 15;     // active < 13
    float acc[8] = {0.f, 0.f, 0.f, 0.f, 0.f, 0.f, 0.f, 0.f};
    int total = 0;
    for (int p = 0; p < P; p++) {
        int s = row_start[p * NN + n], e = row_start[p * NN + n + 1];
        total += e - s;
        for (int base = s; base < e; base += 64) {
            int cn = e - base; if (cn > 64) cn = 64;
            int vidx = (lane < cn) ? csr[base + lane] : 0;
            for (int r = 0; r < cn; r += 8) {
                int sA = r + esub, sB = r + esub + 4;
                int iA = __shfl(vidx, sA, 64);
                int iB = __shfl(vidx, sB, 64);
                if (dg < 13) {
                    if (sA < cn) {
                        const uint4 pk = *reinterpret_cast<const uint4*>(y1 + (size_t)iA * D1P + dg * 8);
                        acc[0] += bflo(pk.x); acc[1] += bfhi(pk.x);
                        acc[2] += bflo(pk.y); acc[3] += bfhi(pk.y);
                        acc[4] += bflo(pk.z); acc[5] += bfhi(pk.z);
                        acc[6] += bflo(pk.w); acc[7] += bfhi(pk.w);
                    }
                    if (sB < cn) {
                        const uint4 pk = *reinterpret_cast<const uint4*>(y1 + (size_t)iB * D1P + dg * 8);
                        acc[0] += bflo(pk.x); acc[1] += bfhi(pk.x);
                        acc[2] += bflo(pk.y); acc[3] += bfhi(pk.y);
                        acc[4] += bflo(pk.z); acc[5] += bfhi(pk.z);
                        acc[6] += bflo(pk.w); acc[7] += bfhi(pk.w);
                    }
                }
            }
        }
    }
#pragma unroll
    for (int j = 0; j < 8; j++) {
        acc[j] += __shfl_xor(acc[j], 16, 64);
        acc[j] += __shfl_xor(acc[j], 32, 64);
    }
    if (esub == 0 && dg < 13) {
        float res[8];
        if (total > 0) {
            float inv = 1.f / (float)total;
#pragma unroll
            for (int j = 0; j < 8; j++) res[j] = acc[j] * inv;
        } else {
            const uint4 pk = *reinterpret_cast<const uint4*>(y1 + (size_t)n * D1P + dg * 8);
            res[0] = bflo(pk.x); res[1] = bfhi(pk.x);
            res[2] = bflo(pk.y); res[3] = bfhi(pk.y);
            res[4] = bflo(pk.z); res[5] = bfhi(pk.z);
            res[6] = bflo(pk.w); res[7] = bfhi(pk.w);
        }
        int d0 = dg * 8;
#pragma unroll
        for (int j = 0; j < 4; j++) h1s[w][d0 + j] = fmaxf(res[j] + b1[d0 + j], 0.f);
        if (dg < 12) {
#pragma unroll
            for (int j = 4; j < 8; j++) h1s[w][d0 + j] = fmaxf(res[j] + b1[d0 + j], 0.f);
        }
    }
    __syncthreads();
    // phase 2: y2[n][j] = h1[n,:] @ W2[:,j]  (bf16 out, stride 24, pads zeroed)
    int j = lane & 31;
    int half = lane >> 5;
    float a2 = 0.f;
    if (j < D2) {
        const float* hr = h1s[w];
        int k0 = half * 50;
#pragma unroll 10
        for (int kk = 0; kk < 50; kk++) a2 += hr[k0 + kk] * W2s[(k0 + kk) * D2 + j];
    }
    a2 += __shfl_xor(a2, 32, 64);
    if (half == 0) {
        if (j < D2) y2b[(size_t)n * D2P + j] = f2bf(a2);
        else if (j < D2P) y2b[(size_t)n * D2P + j] = 0;
    }
}

// ---------------- K6: agg2 (mean over 8 partitions of y2 bf16) -> h2 fp32 ----------------
__global__ __launch_bounds__(256) void k_agg2(const unsigned short* __restrict__ y2b,
        const int* __restrict__ csr, const int* __restrict__ row_start,
        const float* __restrict__ b2, float* __restrict__ h2) {
    int tid = threadIdx.x;
    int n = blockIdx.x * 4 + (tid >> 6);
    int lane = tid & 63;
    int esub = lane >> 2;   // 0..15
    int dg = lane & 3;      // active < 3 (8 dims each; dims 20..23 are zero pads)
    float acc[8] = {0.f, 0.f, 0.f, 0.f, 0.f, 0.f, 0.f, 0.f};
    int total = 0;
    for (int p = 0; p < P; p++) {
        int s = row_start[p * NN + n], e = row_start[p * NN + n + 1];
        total += e - s;
        for (int base = s; base < e; base += 64) {
            int cn = e - base; if (cn > 64) cn = 64;
            int vidx = (lane < cn) ? csr[base + lane] : 0;
            for (int r = 0; r < cn; r += 32) {
                int sA = r + esub, sB = r + esub + 16;
                int iA = __shfl(vidx, sA, 64);
                int iB = __shfl(vidx, sB, 64);
                if (dg < 3) {
                    if (sA < cn) {
                        const uint4 pk = *reinterpret_cast<const uint4*>(y2b + (size_t)iA * D2P + dg * 8);
                        acc[0] += bflo(pk.x); acc[1] += bfhi(pk.x);
                        acc[2] += bflo(pk.y); acc[3] += bfhi(pk.y);
                        acc[4] += bflo(pk.z); acc[5] += bfhi(pk.z);
                        acc[6] += bflo(pk.w); acc[7] += bfhi(pk.w);
                    }
                    if (sB < cn) {
                        const uint4 pk = *reinterpret_cast<const uint4*>(y2b + (size_t)iB * D2P + dg * 8);
                        acc[0] += bflo(pk.x); acc[1] += bfhi(pk.x);
                        acc[2] += bflo(pk.y); acc[3] += bfhi(pk.y);
                        acc[4] += bflo(pk.z); acc[5] += bfhi(pk.z);
                        acc[6] += bflo(pk.w); acc[7] += bfhi(pk.w);
                    }
                }
            }
        }
    }
#pragma unroll
    for (int j = 0; j < 8; j++) {
        acc[j] += __shfl_xor(acc[j], 4, 64);
        acc[j] += __shfl_xor(acc[j], 8, 64);
        acc[j] += __shfl_xor(acc[j], 16, 64);
        acc[j] += __shfl_xor(acc[j], 32, 64);
    }
    if (esub == 0 && dg < 3) {
        float res[8];
        if (total > 0) {
            float inv = 1.f / (float)total;
#pragma unroll
            for (int j = 0; j < 8; j++) res[j] = acc[j] * inv;
        } else {
            const uint4 pk = *reinterpret_cast<const uint4*>(y2b + (size_t)n * D2P + dg * 8);
            res[0] = bflo(pk.x); res[1] = bfhi(pk.x);
            res[2] = bflo(pk.y); res[3] = bfhi(pk.y);
            res[4] = bflo(pk.z); res[5] = bfhi(pk.z);
            res[6] = bflo(pk.w); res[7] = bfhi(pk.w);
        }
        int d0 = dg * 8;
        float* orow = h2 + (size_t)n * D2;
        if (dg < 2) {
#pragma unroll
            for (int j = 0; j < 8; j++) res[j] = fmaxf(res[j] + b2[d0 + j], 0.f);
            *reinterpret_cast<float4*>(orow + d0) = make_float4(res[0], res[1], res[2], res[3]);
            *reinterpret_cast<float4*>(orow + d0 + 4) = make_float4(res[4], res[5], res[6], res[7]);
        } else {
#pragma unroll
            for (int j = 0; j < 4; j++) res[j] = fmaxf(res[j] + b2[d0 + j], 0.f);
            *reinterpret_cast<float4*>(orow + d0) = make_float4(res[0], res[1], res[2], res[3]);
        }
    }
}

// ---------------- K7: pooling + gate + MLP, one block per graph ----------------
__global__ __launch_bounds__(256) void k_pool(const float* __restrict__ h2,
        const int* __restrict__ graph_start, const float* __restrict__ self_feat,
        const float* __restrict__ Wp, const float* __restrict__ bp,
        const float* __restrict__ Wf1, const float* __restrict__ bf1,
        const float* __restrict__ Wf2, const float* __restrict__ bf2,
        float* __restrict__ out) {
    __shared__ float red[8][D2];
    __shared__ float fbuf[D2];
    __shared__ float rbuf[10];
    int g = blockIdx.x;
    int start = graph_start[g], end = graph_start[g + 1];
    int tid = threadIdx.x;
    int j = tid & 31;
    int rs = tid >> 5;
    float a = 0.f;
    if (j < D2)
        for (int i = start + rs; i < end; i += 8) a += h2[(size_t)i * D2 + j];
    if (j < D2) red[rs][j] = a;
    __syncthreads();
    if (tid < D2) {
        float sum = 0.f;
#pragma unroll
        for (int k = 0; k < 8; k++) sum += red[k][tid];
        float m = (float)(end - start);
        float hg = sum / fmaxf(m, 1.f);
        float z = bp[tid];
        const float* sf = self_feat + g * DSELF;
        for (int k = 0; k < DSELF; k++) z += sf[k] * Wp[k * D2 + tid];
        float gate = 1.f / (1.f + expf(-hg * z));
        fbuf[tid] = gate * hg + (1.f - gate) * z;
    }
    __syncthreads();
    if (tid < 10) {
        float a2 = bf1[tid];
        for (int k = 0; k < D2; k++) a2 += fbuf[k] * Wf1[k * 10 + tid];
        rbuf[tid] = fmaxf(a2, 0.f);
    }
    __syncthreads();
    if (tid == 0) {
        float o = bf2[0];
        for (int k = 0; k < 10; k++) o += rbuf[k] * Wf2[k];
        out[g] = o;
    }
}

// ---------------- launch ----------------

extern "C" void kernel_launch(void* const* d_in, const int* in_sizes, int n_in,
                              void* d_out, int out_size, void* d_ws, size_t ws_size,
                              hipStream_t stream) {
    const float* feat      = (const float*)d_in[0];
    const int*   src       = (const int*)d_in[1];
    const int*   dst       = (const int*)d_in[2];
    const int*   gid       = (const int*)d_in[3];
    const float* self_feat = (const float*)d_in[4];
    const float* W1  = (const float*)d_in[5];
    const float* b1  = (const float*)d_in[6];
    const float* W2  = (const float*)d_in[7];
    const float* b2  = (const float*)d_in[8];
    const float* Wp  = (const float*)d_in[9];
    const float* bp  = (const float*)d_in[10];
    const float* Wf1 = (const float*)d_in[11];
    const float* bf1 = (const float*)d_in[12];
    const float* Wf2 = (const float*)d_in[13];
    const float* bf2 = (const float*)d_in[14];
    float* out = (float*)d_out;

    char* ws = (char*)d_ws;
    int*            deg         = (int*)(ws + 0);          // 8*50000 ints (1.6 MB)
    int*            cursor      = (int*)(ws + 1600000);    // 8*50000 ints (1.6 MB)
    int*            row_start   = (int*)(ws + 3200000);    // 400001 ints
    int*            graph_start = (int*)(ws + 4800016);    // 257 ints
    int*            csr         = (int*)(ws + 4801056);    // 1.6M ints -> ends 11201056
    unsigned short* y1bf        = (unsigned short*)(ws + 11201056); // 50000*104 bf16 -> 21601056
    unsigned short* y2b         = (unsigned short*)(ws + 21601056); // 50000*24 bf16 -> 24001056
    float*          h2          = (float*)(ws + 24001056); // 50000*20 fp32 -> 28001056

    hipMemsetAsync(deg, 0, 3200000, stream);   // deg + cursor (contiguous)

    k_deg_mark<<<DEG_BLOCKS + 196, 256, 0, stream>>>(dst, deg, gid, graph_start);
    k_scan<<<1, 1024, 0, stream>>>(deg, row_start);
    k_fill<<<DEG_BLOCKS, 256, 0, stream>>>(src, dst, row_start, cursor, csr);

    k_gemm1<<<1250, 256, 0, stream>>>(feat, W1, y1bf);
    k_agg1g2<<<12500, 256, 0, stream>>>(y1bf, csr, row_start, b1, W2, y2b);
    k_agg2<<<12500, 256, 0, stream>>>(y2b, csr, row_start, b2, h2);
    k_pool<<<NG, 256, 0, stream>>>(h2, graph_start, self_feat, Wp, bp, Wf1, bf1, Wf2, bf2, out);
}

// Round 5
// 437.137 us; speedup vs baseline: 2.7682x; 2.7682x over previous
//
#include <hip/hip_runtime.h>
#include <hip/hip_bf16.h>
#include <math.h>

#define NN 50000
#define NE 1600000
#define NG 256
#define DIN 128
#define D1 100
#define D1P 104      // bf16 row stride for y1
#define D2 20
#define D2P 24       // bf16 row stride for y2 (48 B)
#define DSELF 64
#define P 8          // XCD partitions
#define PN (P * NN)  // 400000

static __device__ __forceinline__ unsigned short f2bf(float x) {
    __hip_bfloat16 h = __float2bfloat16(x);
    unsigned short u;
    __builtin_memcpy(&u, &h, 2);
    return u;
}
static __device__ __forceinline__ float bflo(unsigned u) {
    union { unsigned i; float f; } c; c.i = u << 16; return c.f;
}
static __device__ __forceinline__ float bfhi(unsigned u) {
    union { unsigned i; float f; } c; c.i = u & 0xffff0000u; return c.f;
}

// ---------------- K1: degree count (XCD-partitioned) + graph_start marks ----------------
#define DEG_BLOCKS 1563
__global__ __launch_bounds__(256) void k_deg_mark(const int* __restrict__ dst,
        int* __restrict__ deg, const int* __restrict__ gid, int* __restrict__ graph_start) {
    int b = blockIdx.x;
    if (b < DEG_BLOCKS) {
        int e0 = (b * 256 + threadIdx.x) * 4;
        if (e0 < NE) {
            int4 d = *reinterpret_cast<const int4*>(dst + e0);
            int off = (b & 7) * NN;
            atomicAdd(&deg[off + d.x], 1);
            atomicAdd(&deg[off + d.y], 1);
            atomicAdd(&deg[off + d.z], 1);
            atomicAdd(&deg[off + d.w], 1);
        }
    } else {
        int i = (b - DEG_BLOCKS) * 256 + threadIdx.x;
        if (i >= NN) return;
        int g = gid[i];
        if (i == 0) {
            for (int x = 0; x <= g; x++) graph_start[x] = 0;
        } else {
            int p = gid[i - 1];
            if (p != g) for (int x = p + 1; x <= g; x++) graph_start[x] = i;
        }
        if (i == NN - 1) for (int x = g + 1; x <= NG; x++) graph_start[x] = NN;
    }
}

// ---------------- K2: hierarchical exclusive scan deg[0..PN) -> row_start ----------------
#define SCAN_BLOCKS 98   // ceil(400000 / 4096)

__global__ __launch_bounds__(1024) void k_scan1(const int* __restrict__ deg,
        int* __restrict__ row_start, int* __restrict__ blksum) {
    __shared__ int ps[1024];
    int tid = threadIdx.x;
    int base = blockIdx.x * 4096 + tid * 4;
    int4 v = make_int4(0, 0, 0, 0);
    if (base < PN) v = *reinterpret_cast<const int4*>(deg + base);  // PN % 4 == 0
    int s = v.x + v.y + v.z + v.w;
    ps[tid] = s;
    __syncthreads();
    for (int off = 1; off < 1024; off <<= 1) {
        int t = (tid >= off) ? ps[tid - off] : 0;
        __syncthreads();
        ps[tid] += t;
        __syncthreads();
    }
    if (base < PN) {
        int excl = ps[tid] - s;
        row_start[base] = excl;         excl += v.x;
        row_start[base + 1] = excl;     excl += v.y;
        row_start[base + 2] = excl;     excl += v.z;
        row_start[base + 3] = excl;
    }
    if (tid == 1023) blksum[blockIdx.x] = ps[1023];
}

__global__ __launch_bounds__(128) void k_scan2(const int* __restrict__ blksum,
        int* __restrict__ blkoff, int* __restrict__ row_start) {
    __shared__ int ps[128];
    int tid = threadIdx.x;
    int v = (tid < SCAN_BLOCKS) ? blksum[tid] : 0;
    ps[tid] = v;
    __syncthreads();
    for (int off = 1; off < 128; off <<= 1) {
        int t = (tid >= off) ? ps[tid - off] : 0;
        __syncthreads();
        ps[tid] += t;
        __syncthreads();
    }
    if (tid < SCAN_BLOCKS) blkoff[tid] = ps[tid] - v;
    if (tid == 127) row_start[PN] = ps[127];
}

__global__ __launch_bounds__(1024) void k_scan3(int* __restrict__ row_start,
        const int* __restrict__ blkoff) {
    int base = blockIdx.x * 4096 + threadIdx.x * 4;
    if (base >= PN) return;
    int o = blkoff[blockIdx.x];
    if (o == 0) return;
    int4 v = *reinterpret_cast<int4*>(row_start + base);
    v.x += o; v.y += o; v.z += o; v.w += o;
    *reinterpret_cast<int4*>(row_start + base) = v;
}

// ---------------- K3: CSR fill (XCD-partitioned) ----------------
__global__ __launch_bounds__(256) void k_fill(const int* __restrict__ src,
        const int* __restrict__ dst, const int* __restrict__ row_start,
        int* __restrict__ cursor, int* __restrict__ csr) {
    int b = blockIdx.x;
    int e0 = (b * 256 + threadIdx.x) * 4;
    if (e0 >= NE) return;
    int4 d = *reinterpret_cast<const int4*>(dst + e0);
    int4 sv = *reinterpret_cast<const int4*>(src + e0);
    int off = (b & 7) * NN;
    {
        int pd = off + d.x; int slot = atomicAdd(&cursor[pd], 1);
        csr[row_start[pd] + slot] = sv.x;
    }
    {
        int pd = off + d.y; int slot = atomicAdd(&cursor[pd], 1);
        csr[row_start[pd] + slot] = sv.y;
    }
    {
        int pd = off + d.z; int slot = atomicAdd(&cursor[pd], 1);
        csr[row_start[pd] + slot] = sv.z;
    }
    {
        int pd = off + d.w; int slot = atomicAdd(&cursor[pd], 1);
        csr[row_start[pd] + slot] = sv.w;
    }
}

// ---------------- K4: gemm1: y1 = feat @ W1 (bf16 out), W1 bf16 + feat tile in LDS ----------
__global__ __launch_bounds__(256) void k_gemm1(const float* __restrict__ feat,
        const float* __restrict__ W1, unsigned short* __restrict__ y1) {
    __shared__ unsigned short W1s[DIN * D1];   // 25.6 KB bf16 [k][100]
    __shared__ float feats[40 * DIN];          // 20.5 KB
    int tid = threadIdx.x;
    int n0 = blockIdx.x * 40;
    for (int i = 0; i < 25; i++) {
        int f2 = tid + 256 * i;   // < 6400
        float2 w = *reinterpret_cast<const float2*>(W1 + f2 * 2);
        unsigned pack = (unsigned)f2bf(w.x) | ((unsigned)f2bf(w.y) << 16);
        *reinterpret_cast<unsigned*>(W1s + f2 * 2) = pack;
    }
    for (int i = 0; i < 5; i++) {
        int f4 = tid + 256 * i;   // < 1280
        *reinterpret_cast<float4*>(feats + f4 * 4) =
            *reinterpret_cast<const float4*>(feat + (size_t)n0 * DIN + f4 * 4);
    }
    __syncthreads();
    if (tid >= 250) return;
    int cg = tid % 25, rg = tid / 25;
    float acc[4][4];
#pragma unroll
    for (int i = 0; i < 4; i++)
#pragma unroll
        for (int j = 0; j < 4; j++) acc[i][j] = 0.f;
    const float* f0 = feats + (rg * 4 + 0) * DIN;
    const float* f1 = feats + (rg * 4 + 1) * DIN;
    const float* f2 = feats + (rg * 4 + 2) * DIN;
    const float* f3 = feats + (rg * 4 + 3) * DIN;
#pragma unroll 4
    for (int k = 0; k < DIN; k++) {
        ushort4 wp = *reinterpret_cast<const ushort4*>(W1s + k * D1 + cg * 4);
        float w0 = bflo(wp.x), w1 = bflo(wp.y), w2 = bflo(wp.z), w3 = bflo(wp.w);
        float a0 = f0[k], a1 = f1[k], a2 = f2[k], a3 = f3[k];
        acc[0][0] += a0 * w0; acc[0][1] += a0 * w1; acc[0][2] += a0 * w2; acc[0][3] += a0 * w3;
        acc[1][0] += a1 * w0; acc[1][1] += a1 * w1; acc[1][2] += a1 * w2; acc[1][3] += a1 * w3;
        acc[2][0] += a2 * w0; acc[2][1] += a2 * w1; acc[2][2] += a2 * w2; acc[2][3] += a2 * w3;
        acc[3][0] += a3 * w0; acc[3][1] += a3 * w1; acc[3][2] += a3 * w2; acc[3][3] += a3 * w3;
    }
#pragma unroll
    for (int i = 0; i < 4; i++) {
        int n = n0 + rg * 4 + i;
        ushort4 st;
        st.x = f2bf(acc[i][0]); st.y = f2bf(acc[i][1]);
        st.z = f2bf(acc[i][2]); st.w = f2bf(acc[i][3]);
        *reinterpret_cast<ushort4*>(y1 + (size_t)n * D1P + cg * 4) = st;
        if (cg == 24) {
            ushort4 z; z.x = z.y = z.z = z.w = 0;
            *reinterpret_cast<ushort4*>(y1 + (size_t)n * D1P + 100) = z;
        }
    }
}

// ---------------- K5: agg1 (mean over 8 csr partitions) + fused gemm2 -> y2 bf16 --------
__global__ __launch_bounds__(256) void k_agg1g2(const unsigned short* __restrict__ y1,
        const int* __restrict__ csr, const int* __restrict__ row_start,
        const float* __restrict__ b1, const float* __restrict__ W2,
        unsigned short* __restrict__ y2b) {
    __shared__ float W2s[D1 * D2];   // 8 KB
    __shared__ float h1s[4][D1P];
    int tid = threadIdx.x;
    for (int i = 0; i < 2; i++) {
        int f4 = tid + 256 * i;
        if (f4 < 500)
            *reinterpret_cast<float4*>(W2s + f4 * 4) =
                *reinterpret_cast<const float4*>(W2 + f4 * 4);
    }
    int w = tid >> 6;
    int n = blockIdx.x * 4 + w;
    int lane = tid & 63;
    int esub = lane >> 4;   // 0..3
    int dg = lane & 15;     // active < 13
    float acc[8] = {0.f, 0.f, 0.f, 0.f, 0.f, 0.f, 0.f, 0.f};
    int total = 0;
    for (int p = 0; p < P; p++) {
        int s = row_start[p * NN + n], e = row_start[p * NN + n + 1];
        total += e - s;
        for (int base = s; base < e; base += 64) {
            int cn = e - base; if (cn > 64) cn = 64;
            int vidx = (lane < cn) ? csr[base + lane] : 0;
            for (int r = 0; r < cn; r += 8) {
                int sA = r + esub, sB = r + esub + 4;
                int iA = __shfl(vidx, sA, 64);
                int iB = __shfl(vidx, sB, 64);
                if (dg < 13) {
                    if (sA < cn) {
                        const uint4 pk = *reinterpret_cast<const uint4*>(y1 + (size_t)iA * D1P + dg * 8);
                        acc[0] += bflo(pk.x); acc[1] += bfhi(pk.x);
                        acc[2] += bflo(pk.y); acc[3] += bfhi(pk.y);
                        acc[4] += bflo(pk.z); acc[5] += bfhi(pk.z);
                        acc[6] += bflo(pk.w); acc[7] += bfhi(pk.w);
                    }
                    if (sB < cn) {
                        const uint4 pk = *reinterpret_cast<const uint4*>(y1 + (size_t)iB * D1P + dg * 8);
                        acc[0] += bflo(pk.x); acc[1] += bfhi(pk.x);
                        acc[2] += bflo(pk.y); acc[3] += bfhi(pk.y);
                        acc[4] += bflo(pk.z); acc[5] += bfhi(pk.z);
                        acc[6] += bflo(pk.w); acc[7] += bfhi(pk.w);
                    }
                }
            }
        }
    }
#pragma unroll
    for (int j = 0; j < 8; j++) {
        acc[j] += __shfl_xor(acc[j], 16, 64);
        acc[j] += __shfl_xor(acc[j], 32, 64);
    }
    if (esub == 0 && dg < 13) {
        float res[8];
        if (total > 0) {
            float inv = 1.f / (float)total;
#pragma unroll
            for (int j = 0; j < 8; j++) res[j] = acc[j] * inv;
        } else {
            const uint4 pk = *reinterpret_cast<const uint4*>(y1 + (size_t)n * D1P + dg * 8);
            res[0] = bflo(pk.x); res[1] = bfhi(pk.x);
            res[2] = bflo(pk.y); res[3] = bfhi(pk.y);
            res[4] = bflo(pk.z); res[5] = bfhi(pk.z);
            res[6] = bflo(pk.w); res[7] = bfhi(pk.w);
        }
        int d0 = dg * 8;
#pragma unroll
        for (int j = 0; j < 4; j++) h1s[w][d0 + j] = fmaxf(res[j] + b1[d0 + j], 0.f);
        if (dg < 12) {
#pragma unroll
            for (int j = 4; j < 8; j++) h1s[w][d0 + j] = fmaxf(res[j] + b1[d0 + j], 0.f);
        }
    }
    __syncthreads();
    int j = lane & 31;
    int half = lane >> 5;
    float a2 = 0.f;
    if (j < D2) {
        const float* hr = h1s[w];
        int k0 = half * 50;
#pragma unroll 10
        for (int kk = 0; kk < 50; kk++) a2 += hr[k0 + kk] * W2s[(k0 + kk) * D2 + j];
    }
    a2 += __shfl_xor(a2, 32, 64);
    if (half == 0) {
        if (j < D2) y2b[(size_t)n * D2P + j] = f2bf(a2);
        else if (j < D2P) y2b[(size_t)n * D2P + j] = 0;
    }
}

// ---------------- K6: agg2 (mean over 8 partitions of y2 bf16) -> h2 fp32 ----------------
__global__ __launch_bounds__(256) void k_agg2(const unsigned short* __restrict__ y2b,
        const int* __restrict__ csr, const int* __restrict__ row_start,
        const float* __restrict__ b2, float* __restrict__ h2) {
    int tid = threadIdx.x;
    int n = blockIdx.x * 4 + (tid >> 6);
    int lane = tid & 63;
    int esub = lane >> 2;   // 0..15
    int dg = lane & 3;      // active < 3
    float acc[8] = {0.f, 0.f, 0.f, 0.f, 0.f, 0.f, 0.f, 0.f};
    int total = 0;
    for (int p = 0; p < P; p++) {
        int s = row_start[p * NN + n], e = row_start[p * NN + n + 1];
        total += e - s;
        for (int base = s; base < e; base += 64) {
            int cn = e - base; if (cn > 64) cn = 64;
            int vidx = (lane < cn) ? csr[base + lane] : 0;
            for (int r = 0; r < cn; r += 32) {
                int sA = r + esub, sB = r + esub + 16;
                int iA = __shfl(vidx, sA, 64);
                int iB = __shfl(vidx, sB, 64);
                if (dg < 3) {
                    if (sA < cn) {
                        const uint4 pk = *reinterpret_cast<const uint4*>(y2b + (size_t)iA * D2P + dg * 8);
                        acc[0] += bflo(pk.x); acc[1] += bfhi(pk.x);
                        acc[2] += bflo(pk.y); acc[3] += bfhi(pk.y);
                        acc[4] += bflo(pk.z); acc[5] += bfhi(pk.z);
                        acc[6] += bflo(pk.w); acc[7] += bfhi(pk.w);
                    }
                    if (sB < cn) {
                        const uint4 pk = *reinterpret_cast<const uint4*>(y2b + (size_t)iB * D2P + dg * 8);
                        acc[0] += bflo(pk.x); acc[1] += bfhi(pk.x);
                        acc[2] += bflo(pk.y); acc[3] += bfhi(pk.y);
                        acc[4] += bflo(pk.z); acc[5] += bfhi(pk.z);
                        acc[6] += bflo(pk.w); acc[7] += bfhi(pk.w);
                    }
                }
            }
        }
    }
#pragma unroll
    for (int j = 0; j < 8; j++) {
        acc[j] += __shfl_xor(acc[j], 4, 64);
        acc[j] += __shfl_xor(acc[j], 8, 64);
        acc[j] += __shfl_xor(acc[j], 16, 64);
        acc[j] += __shfl_xor(acc[j], 32, 64);
    }
    if (esub == 0 && dg < 3) {
        float res[8];
        if (total > 0) {
            float inv = 1.f / (float)total;
#pragma unroll
            for (int j = 0; j < 8; j++) res[j] = acc[j] * inv;
        } else {
            const uint4 pk = *reinterpret_cast<const uint4*>(y2b + (size_t)n * D2P + dg * 8);
            res[0] = bflo(pk.x); res[1] = bfhi(pk.x);
            res[2] = bflo(pk.y); res[3] = bfhi(pk.y);
            res[4] = bflo(pk.z); res[5] = bfhi(pk.z);
            res[6] = bflo(pk.w); res[7] = bfhi(pk.w);
        }
        int d0 = dg * 8;
        float* orow = h2 + (size_t)n * D2;
        if (dg < 2) {
#pragma unroll
            for (int j = 0; j < 8; j++) res[j] = fmaxf(res[j] + b2[d0 + j], 0.f);
            *reinterpret_cast<float4*>(orow + d0) = make_float4(res[0], res[1], res[2], res[3]);
            *reinterpret_cast<float4*>(orow + d0 + 4) = make_float4(res[4], res[5], res[6], res[7]);
        } else {
#pragma unroll
            for (int j = 0; j < 4; j++) res[j] = fmaxf(res[j] + b2[d0 + j], 0.f);
            *reinterpret_cast<float4*>(orow + d0) = make_float4(res[0], res[1], res[2], res[3]);
        }
    }
}

// ---------------- K7: pooling + gate + MLP, one block per graph ----------------
__global__ __launch_bounds__(256) void k_pool(const float* __restrict__ h2,
        const int* __restrict__ graph_start, const float* __restrict__ self_feat,
        const float* __restrict__ Wp, const float* __restrict__ bp,
        const float* __restrict__ Wf1, const float* __restrict__ bf1,
        const float* __restrict__ Wf2, const float* __restrict__ bf2,
        float* __restrict__ out) {
    __shared__ float red[8][D2];
    __shared__ float fbuf[D2];
    __shared__ float rbuf[10];
    int g = blockIdx.x;
    int start = graph_start[g], end = graph_start[g + 1];
    int tid = threadIdx.x;
    int j = tid & 31;
    int rs = tid >> 5;
    float a = 0.f;
    if (j < D2)
        for (int i = start + rs; i < end; i += 8) a += h2[(size_t)i * D2 + j];
    if (j < D2) red[rs][j] = a;
    __syncthreads();
    if (tid < D2) {
        float sum = 0.f;
#pragma unroll
        for (int k = 0; k < 8; k++) sum += red[k][tid];
        float m = (float)(end - start);
        float hg = sum / fmaxf(m, 1.f);
        float z = bp[tid];
        const float* sf = self_feat + g * DSELF;
        for (int k = 0; k < DSELF; k++) z += sf[k] * Wp[k * D2 + tid];
        float gate = 1.f / (1.f + expf(-hg * z));
        fbuf[tid] = gate * hg + (1.f - gate) * z;
    }
    __syncthreads();
    if (tid < 10) {
        float a2 = bf1[tid];
        for (int k = 0; k < D2; k++) a2 += fbuf[k] * Wf1[k * 10 + tid];
        rbuf[tid] = fmaxf(a2, 0.f);
    }
    __syncthreads();
    if (tid == 0) {
        float o = bf2[0];
        for (int k = 0; k < 10; k++) o += rbuf[k] * Wf2[k];
        out[g] = o;
    }
}

// ---------------- launch ----------------

extern "C" void kernel_launch(void* const* d_in, const int* in_sizes, int n_in,
                              void* d_out, int out_size, void* d_ws, size_t ws_size,
                              hipStream_t stream) {
    const float* feat      = (const float*)d_in[0];
    const int*   src       = (const int*)d_in[1];
    const int*   dst       = (const int*)d_in[2];
    const int*   gid       = (const int*)d_in[3];
    const float* self_feat = (const float*)d_in[4];
    const float* W1  = (const float*)d_in[5];
    const float* b1  = (const float*)d_in[6];
    const float* W2  = (const float*)d_in[7];
    const float* b2  = (const float*)d_in[8];
    const float* Wp  = (const float*)d_in[9];
    const float* bp  = (const float*)d_in[10];
    const float* Wf1 = (const float*)d_in[11];
    const float* bf1 = (const float*)d_in[12];
    const float* Wf2 = (const float*)d_in[13];
    const float* bf2 = (const float*)d_in[14];
    float* out = (float*)d_out;

    char* ws = (char*)d_ws;
    int*            deg         = (int*)(ws + 0);          // 400000 ints (1.6 MB)
    int*            cursor      = (int*)(ws + 1600000);    // 400000 ints (1.6 MB)
    int*            row_start   = (int*)(ws + 3200000);    // 400001 ints
    int*            graph_start = (int*)(ws + 4800016);    // 257 ints
    int*            blksum      = (int*)(ws + 4801056);    // 98 ints
    int*            blkoff      = (int*)(ws + 4801568);    // 98 ints
    int*            csr         = (int*)(ws + 4802080);    // 1.6M ints -> ends 11202080
    unsigned short* y1bf        = (unsigned short*)(ws + 11202080); // 50000*104 bf16
    unsigned short* y2b         = (unsigned short*)(ws + 21602080); // 50000*24 bf16
    float*          h2          = (float*)(ws + 24002080); // 50000*20 fp32 -> 28002080

    hipMemsetAsync(deg, 0, 3200000, stream);   // deg + cursor (contiguous)

    k_deg_mark<<<DEG_BLOCKS + 196, 256, 0, stream>>>(dst, deg, gid, graph_start);
    k_scan1<<<SCAN_BLOCKS, 1024, 0, stream>>>(deg, row_start, blksum);
    k_scan2<<<1, 128, 0, stream>>>(blksum, blkoff, row_start);
    k_scan3<<<SCAN_BLOCKS, 1024, 0, stream>>>(row_start, blkoff);
    k_fill<<<DEG_BLOCKS, 256, 0, stream>>>(src, dst, row_start, cursor, csr);

    k_gemm1<<<1250, 256, 0, stream>>>(feat, W1, y1bf);
    k_agg1g2<<<12500, 256, 0, stream>>>(y1bf, csr, row_start, b1, W2, y2b);
    k_agg2<<<12500, 256, 0, stream>>>(y2b, csr, row_start, b2, h2);
    k_pool<<<NG, 256, 0, stream>>>(h2, graph_start, self_feat, Wp, bp, Wf1, bf1, Wf2, bf2, out);
}

// Round 7
// 373.773 us; speedup vs baseline: 3.2375x; 1.1695x over previous
//
#include <hip/hip_runtime.h>
#include <hip/hip_bf16.h>
#include <math.h>

#define NN 50000
#define NE 1600000
#define NG 256
#define DIN 128
#define D1 100
#define D1P 104      // bf16 row stride for y1 (208 B)
#define D2 20
#define D2P 24       // bf16 row stride for y2 (48 B)
#define DSELF 64
#define P 8          // XCD partitions
#define PN (P * NN)  // 400000
#define CAP 128      // merged-CSR per-node capacity (max deg ~66 for Poisson(32))

static __device__ __forceinline__ unsigned short f2bf(float x) {
    __hip_bfloat16 h = __float2bfloat16(x);
    unsigned short u;
    __builtin_memcpy(&u, &h, 2);
    return u;
}
static __device__ __forceinline__ float bflo(unsigned u) {
    union { unsigned i; float f; } c; c.i = u << 16; return c.f;
}
static __device__ __forceinline__ float bfhi(unsigned u) {
    union { unsigned i; float f; } c; c.i = u & 0xffff0000u; return c.f;
}

// ---------------- K1: degree count (XCD-partitioned) + graph_start marks ----------------
#define DEG_BLOCKS 1563
__global__ __launch_bounds__(256) void k_deg_mark(const int* __restrict__ dst,
        int* __restrict__ deg, const int* __restrict__ gid, int* __restrict__ graph_start) {
    int b = blockIdx.x;
    if (b < DEG_BLOCKS) {
        int e0 = (b * 256 + threadIdx.x) * 4;
        if (e0 < NE) {
            int4 d = *reinterpret_cast<const int4*>(dst + e0);
            int off = (b & 7) * NN;
            atomicAdd(&deg[off + d.x], 1);
            atomicAdd(&deg[off + d.y], 1);
            atomicAdd(&deg[off + d.z], 1);
            atomicAdd(&deg[off + d.w], 1);
        }
    } else {
        int i = (b - DEG_BLOCKS) * 256 + threadIdx.x;
        if (i >= NN) return;
        int g = gid[i];
        if (i == 0) {
            for (int x = 0; x <= g; x++) graph_start[x] = 0;
        } else {
            int p = gid[i - 1];
            if (p != g) for (int x = p + 1; x <= g; x++) graph_start[x] = i;
        }
        if (i == NN - 1) for (int x = g + 1; x <= NG; x++) graph_start[x] = NN;
    }
}

// ---------------- K2: hierarchical exclusive scan deg[0..PN) -> row_start ----------------
#define SCAN_BLOCKS 98   // ceil(400000 / 4096)

__global__ __launch_bounds__(1024) void k_scan1(const int* __restrict__ deg,
        int* __restrict__ row_start, int* __restrict__ blksum) {
    __shared__ int ps[1024];
    int tid = threadIdx.x;
    int base = blockIdx.x * 4096 + tid * 4;
    int4 v = make_int4(0, 0, 0, 0);
    if (base < PN) v = *reinterpret_cast<const int4*>(deg + base);
    int s = v.x + v.y + v.z + v.w;
    ps[tid] = s;
    __syncthreads();
    for (int off = 1; off < 1024; off <<= 1) {
        int t = (tid >= off) ? ps[tid - off] : 0;
        __syncthreads();
        ps[tid] += t;
        __syncthreads();
    }
    if (base < PN) {
        int excl = ps[tid] - s;
        row_start[base] = excl;         excl += v.x;
        row_start[base + 1] = excl;     excl += v.y;
        row_start[base + 2] = excl;     excl += v.z;
        row_start[base + 3] = excl;
    }
    if (tid == 1023) blksum[blockIdx.x] = ps[1023];
}

__global__ __launch_bounds__(128) void k_scan2(const int* __restrict__ blksum,
        int* __restrict__ blkoff, int* __restrict__ row_start) {
    __shared__ int ps[128];
    int tid = threadIdx.x;
    int v = (tid < SCAN_BLOCKS) ? blksum[tid] : 0;
    ps[tid] = v;
    __syncthreads();
    for (int off = 1; off < 128; off <<= 1) {
        int t = (tid >= off) ? ps[tid - off] : 0;
        __syncthreads();
        ps[tid] += t;
        __syncthreads();
    }
    if (tid < SCAN_BLOCKS) blkoff[tid] = ps[tid] - v;
    if (tid == 127) row_start[PN] = ps[127];
}

__global__ __launch_bounds__(1024) void k_scan3(int* __restrict__ row_start,
        const int* __restrict__ blkoff) {
    int base = blockIdx.x * 4096 + threadIdx.x * 4;
    if (base >= PN) return;
    int o = blkoff[blockIdx.x];
    if (o == 0) return;
    int4 v = *reinterpret_cast<int4*>(row_start + base);
    v.x += o; v.y += o; v.z += o; v.w += o;
    *reinterpret_cast<int4*>(row_start + base) = v;
}

// ---------------- K3: CSR fill (XCD-partitioned) ----------------
__global__ __launch_bounds__(256) void k_fill(const int* __restrict__ src,
        const int* __restrict__ dst, const int* __restrict__ row_start,
        int* __restrict__ cursor, int* __restrict__ csr) {
    int b = blockIdx.x;
    int e0 = (b * 256 + threadIdx.x) * 4;
    if (e0 >= NE) return;
    int4 d = *reinterpret_cast<const int4*>(dst + e0);
    int4 sv = *reinterpret_cast<const int4*>(src + e0);
    int off = (b & 7) * NN;
    { int pd = off + d.x; int sl = atomicAdd(&cursor[pd], 1); csr[row_start[pd] + sl] = sv.x; }
    { int pd = off + d.y; int sl = atomicAdd(&cursor[pd], 1); csr[row_start[pd] + sl] = sv.y; }
    { int pd = off + d.z; int sl = atomicAdd(&cursor[pd], 1); csr[row_start[pd] + sl] = sv.z; }
    { int pd = off + d.w; int sl = atomicAdd(&cursor[pd], 1); csr[row_start[pd] + sl] = sv.w; }
}

// ---------------- K3b: merge 8 partitioned segments into padded merged CSR ----------------
// wave per node; slots [tot,128) filled with NN (dummy zero row) so aggregators run branch-free.
__global__ __launch_bounds__(256) void k_merge(const int* __restrict__ csr,
        const int* __restrict__ row_start, int* __restrict__ mcsr, int* __restrict__ mdeg) {
    int tid = threadIdx.x;
    int n = blockIdx.x * 4 + (tid >> 6);
    int lane = tid & 63;
    int sp = 0, len = 0;
    if (lane < 8) {
        sp = row_start[lane * NN + n];
        len = row_start[lane * NN + n + 1] - sp;
    }
    int incl = len;
#pragma unroll
    for (int d = 1; d < 8; d <<= 1) {
        int t = __shfl_up(incl, d, 64);
        if (lane >= d) incl += t;
    }
    int ex = incl - len;
    int ex1 = __shfl(ex, 1, 64), ex2 = __shfl(ex, 2, 64), ex3 = __shfl(ex, 3, 64);
    int ex4 = __shfl(ex, 4, 64), ex5 = __shfl(ex, 5, 64), ex6 = __shfl(ex, 6, 64);
    int ex7 = __shfl(ex, 7, 64);
    int g0 = __shfl(sp, 0, 64), g1 = __shfl(sp, 1, 64), g2 = __shfl(sp, 2, 64);
    int g3 = __shfl(sp, 3, 64), g4 = __shfl(sp, 4, 64), g5 = __shfl(sp, 5, 64);
    int g6 = __shfl(sp, 6, 64), g7 = __shfl(sp, 7, 64);
    int tot = __shfl(incl, 7, 64);
    if (lane == 0) mdeg[n] = tot;
    int* out = mcsr + (n << 7);
#pragma unroll
    for (int t = 0; t < 2; t++) {
        int L = lane + t * 64;
        int v = NN;
        if (L < tot) {
            int pg, pe;
            if      (L >= ex7) { pg = g7; pe = ex7; }
            else if (L >= ex6) { pg = g6; pe = ex6; }
            else if (L >= ex5) { pg = g5; pe = ex5; }
            else if (L >= ex4) { pg = g4; pe = ex4; }
            else if (L >= ex3) { pg = g3; pe = ex3; }
            else if (L >= ex2) { pg = g2; pe = ex2; }
            else if (L >= ex1) { pg = g1; pe = ex1; }
            else               { pg = g0; pe = 0;   }
            v = csr[pg + L - pe];
        }
        out[L] = v;
    }
}

// ---------------- K4: gemm1: y1 = feat @ W1 (bf16 out); also zeroes dummy rows ----------
__global__ __launch_bounds__(256) void k_gemm1(const float* __restrict__ feat,
        const float* __restrict__ W1, unsigned short* __restrict__ y1,
        unsigned short* __restrict__ y2b) {
    __shared__ unsigned short W1s[DIN * D1];   // 25.6 KB bf16 [k][100]
    __shared__ float feats[40 * DIN];          // 20.5 KB
    int tid = threadIdx.x;
    int n0 = blockIdx.x * 40;
    if (blockIdx.x == 0) {   // zero dummy rows (index NN) used by pad gathers
        // y1 dummy row: 104 shorts = 26 ushort4; y2b dummy row: 24 shorts = 6 ushort4.
        // (R6 bug: tid<13 only zeroed 52 of 104 shorts -> stale csr bytes decoded
        //  as bf16 ~2^107 in pad gathers -> absmax 3e21.)
        ushort4 z; z.x = z.y = z.z = z.w = 0;
        if (tid < 26)
            *reinterpret_cast<ushort4*>(y1 + (size_t)NN * D1P + tid * 4) = z;
        else if (tid < 32)
            *reinterpret_cast<ushort4*>(y2b + (size_t)NN * D2P + (tid - 26) * 4) = z;
    }
    for (int i = 0; i < 25; i++) {
        int f2 = tid + 256 * i;   // < 6400
        float2 w = *reinterpret_cast<const float2*>(W1 + f2 * 2);
        unsigned pack = (unsigned)f2bf(w.x) | ((unsigned)f2bf(w.y) << 16);
        *reinterpret_cast<unsigned*>(W1s + f2 * 2) = pack;
    }
    for (int i = 0; i < 5; i++) {
        int f4 = tid + 256 * i;   // < 1280
        *reinterpret_cast<float4*>(feats + f4 * 4) =
            *reinterpret_cast<const float4*>(feat + (size_t)n0 * DIN + f4 * 4);
    }
    __syncthreads();
    if (tid >= 250) return;
    int cg = tid % 25, rg = tid / 25;
    float acc[4][4];
#pragma unroll
    for (int i = 0; i < 4; i++)
#pragma unroll
        for (int j = 0; j < 4; j++) acc[i][j] = 0.f;
    const float* f0 = feats + (rg * 4 + 0) * DIN;
    const float* f1 = feats + (rg * 4 + 1) * DIN;
    const float* f2 = feats + (rg * 4 + 2) * DIN;
    const float* f3 = feats + (rg * 4 + 3) * DIN;
#pragma unroll 4
    for (int k = 0; k < DIN; k++) {
        ushort4 wp = *reinterpret_cast<const ushort4*>(W1s + k * D1 + cg * 4);
        float w0 = bflo(wp.x), w1 = bflo(wp.y), w2 = bflo(wp.z), w3 = bflo(wp.w);
        float a0 = f0[k], a1 = f1[k], a2 = f2[k], a3 = f3[k];
        acc[0][0] += a0 * w0; acc[0][1] += a0 * w1; acc[0][2] += a0 * w2; acc[0][3] += a0 * w3;
        acc[1][0] += a1 * w0; acc[1][1] += a1 * w1; acc[1][2] += a1 * w2; acc[1][3] += a1 * w3;
        acc[2][0] += a2 * w0; acc[2][1] += a2 * w1; acc[2][2] += a2 * w2; acc[2][3] += a2 * w3;
        acc[3][0] += a3 * w0; acc[3][1] += a3 * w1; acc[3][2] += a3 * w2; acc[3][3] += a3 * w3;
    }
#pragma unroll
    for (int i = 0; i < 4; i++) {
        int n = n0 + rg * 4 + i;
        ushort4 st;
        st.x = f2bf(acc[i][0]); st.y = f2bf(acc[i][1]);
        st.z = f2bf(acc[i][2]); st.w = f2bf(acc[i][3]);
        *reinterpret_cast<ushort4*>(y1 + (size_t)n * D1P + cg * 4) = st;
        if (cg == 24) {
            ushort4 z; z.x = z.y = z.z = z.w = 0;
            *reinterpret_cast<ushort4*>(y1 + (size_t)n * D1P + 100) = z;
        }
    }
}

#define ACC8(pk) do { \
    acc[0] += bflo(pk.x); acc[1] += bfhi(pk.x); \
    acc[2] += bflo(pk.y); acc[3] += bfhi(pk.y); \
    acc[4] += bflo(pk.z); acc[5] += bfhi(pk.z); \
    acc[6] += bflo(pk.w); acc[7] += bfhi(pk.w); } while (0)

// ---------------- K5: agg1 (merged CSR, 8 gathers in flight) + fused gemm2 -> y2 bf16 ----
__global__ __launch_bounds__(256) void k_agg1g2(const unsigned short* __restrict__ y1,
        const int* __restrict__ mcsr, const int* __restrict__ mdeg,
        const float* __restrict__ b1, const float* __restrict__ W2,
        unsigned short* __restrict__ y2b) {
    __shared__ float W2s[D1 * D2];   // 8 KB
    __shared__ float h1s[4][D1P];
    int tid = threadIdx.x;
    for (int i = 0; i < 2; i++) {
        int f4 = tid + 256 * i;
        if (f4 < 500)
            *reinterpret_cast<float4*>(W2s + f4 * 4) =
                *reinterpret_cast<const float4*>(W2 + f4 * 4);
    }
    int w = tid >> 6;
    int n = blockIdx.x * 4 + w;
    int lane = tid & 63;
    int esub = lane >> 4;   // 0..3
    int dg = lane & 15;     // active < 13
    int tot = mdeg[n];
    int padded = (tot + 31) & ~31;
    const int* row = mcsr + (n << 7);
    float acc[8] = {0.f, 0.f, 0.f, 0.f, 0.f, 0.f, 0.f, 0.f};
    for (int base = 0; base < padded; base += 32) {
        int vidx = row[base + (lane & 31)];
        int i0 = __shfl(vidx, esub +  0, 64);
        int i1 = __shfl(vidx, esub +  4, 64);
        int i2 = __shfl(vidx, esub +  8, 64);
        int i3 = __shfl(vidx, esub + 12, 64);
        int i4 = __shfl(vidx, esub + 16, 64);
        int i5 = __shfl(vidx, esub + 20, 64);
        int i6 = __shfl(vidx, esub + 24, 64);
        int i7 = __shfl(vidx, esub + 28, 64);
        if (dg < 13) {
            const uint4 p0 = *reinterpret_cast<const uint4*>(y1 + (size_t)i0 * D1P + dg * 8);
            const uint4 p1 = *reinterpret_cast<const uint4*>(y1 + (size_t)i1 * D1P + dg * 8);
            const uint4 p2 = *reinterpret_cast<const uint4*>(y1 + (size_t)i2 * D1P + dg * 8);
            const uint4 p3 = *reinterpret_cast<const uint4*>(y1 + (size_t)i3 * D1P + dg * 8);
            const uint4 p4 = *reinterpret_cast<const uint4*>(y1 + (size_t)i4 * D1P + dg * 8);
            const uint4 p5 = *reinterpret_cast<const uint4*>(y1 + (size_t)i5 * D1P + dg * 8);
            const uint4 p6 = *reinterpret_cast<const uint4*>(y1 + (size_t)i6 * D1P + dg * 8);
            const uint4 p7 = *reinterpret_cast<const uint4*>(y1 + (size_t)i7 * D1P + dg * 8);
            ACC8(p0); ACC8(p1); ACC8(p2); ACC8(p3);
            ACC8(p4); ACC8(p5); ACC8(p6); ACC8(p7);
        }
    }
#pragma unroll
    for (int j = 0; j < 8; j++) {
        acc[j] += __shfl_xor(acc[j], 16, 64);
        acc[j] += __shfl_xor(acc[j], 32, 64);
    }
    if (esub == 0 && dg < 13) {
        float res[8];
        if (tot > 0) {
            float inv = 1.f / (float)tot;
#pragma unroll
            for (int j = 0; j < 8; j++) res[j] = acc[j] * inv;
        } else {
            const uint4 pk = *reinterpret_cast<const uint4*>(y1 + (size_t)n * D1P + dg * 8);
            res[0] = bflo(pk.x); res[1] = bfhi(pk.x);
            res[2] = bflo(pk.y); res[3] = bfhi(pk.y);
            res[4] = bflo(pk.z); res[5] = bfhi(pk.z);
            res[6] = bflo(pk.w); res[7] = bfhi(pk.w);
        }
        int d0 = dg * 8;
#pragma unroll
        for (int j = 0; j < 4; j++) h1s[w][d0 + j] = fmaxf(res[j] + b1[d0 + j], 0.f);
        if (dg < 12) {
#pragma unroll
            for (int j = 4; j < 8; j++) h1s[w][d0 + j] = fmaxf(res[j] + b1[d0 + j], 0.f);
        }
    }
    __syncthreads();
    int j = lane & 31;
    int half = lane >> 5;
    float a2 = 0.f;
    if (j < D2) {
        const float* hr = h1s[w];
        int k0 = half * 50;
#pragma unroll 10
        for (int kk = 0; kk < 50; kk++) a2 += hr[k0 + kk] * W2s[(k0 + kk) * D2 + j];
    }
    a2 += __shfl_xor(a2, 32, 64);
    if (half == 0) {
        if (j < D2) y2b[(size_t)n * D2P + j] = f2bf(a2);
        else if (j < D2P) y2b[(size_t)n * D2P + j] = 0;
    }
}

// ---------------- K6: agg2 (merged CSR, 4 gathers in flight) -> h2 fp32 ----------------
__global__ __launch_bounds__(256) void k_agg2(const unsigned short* __restrict__ y2b,
        const int* __restrict__ mcsr, const int* __restrict__ mdeg,
        const float* __restrict__ b2, float* __restrict__ h2) {
    int tid = threadIdx.x;
    int n = blockIdx.x * 4 + (tid >> 6);
    int lane = tid & 63;
    int esub = lane >> 2;   // 0..15
    int dg = lane & 3;      // active < 3
    int tot = mdeg[n];
    int padded = (tot + 63) & ~63;
    const int* row = mcsr + (n << 7);
    float acc[8] = {0.f, 0.f, 0.f, 0.f, 0.f, 0.f, 0.f, 0.f};
    for (int base = 0; base < padded; base += 64) {
        int vidx = row[base + lane];
        int i0 = __shfl(vidx, esub +  0, 64);
        int i1 = __shfl(vidx, esub + 16, 64);
        int i2 = __shfl(vidx, esub + 32, 64);
        int i3 = __shfl(vidx, esub + 48, 64);
        if (dg < 3) {
            const uint4 p0 = *reinterpret_cast<const uint4*>(y2b + (size_t)i0 * D2P + dg * 8);
            const uint4 p1 = *reinterpret_cast<const uint4*>(y2b + (size_t)i1 * D2P + dg * 8);
            const uint4 p2 = *reinterpret_cast<const uint4*>(y2b + (size_t)i2 * D2P + dg * 8);
            const uint4 p3 = *reinterpret_cast<const uint4*>(y2b + (size_t)i3 * D2P + dg * 8);
            ACC8(p0); ACC8(p1); ACC8(p2); ACC8(p3);
        }
    }
#pragma unroll
    for (int j = 0; j < 8; j++) {
        acc[j] += __shfl_xor(acc[j], 4, 64);
        acc[j] += __shfl_xor(acc[j], 8, 64);
        acc[j] += __shfl_xor(acc[j], 16, 64);
        acc[j] += __shfl_xor(acc[j], 32, 64);
    }
    if (esub == 0 && dg < 3) {
        float res[8];
        if (tot > 0) {
            float inv = 1.f / (float)tot;
#pragma unroll
            for (int j = 0; j < 8; j++) res[j] = acc[j] * inv;
        } else {
            const uint4 pk = *reinterpret_cast<const uint4*>(y2b + (size_t)n * D2P + dg * 8);
            res[0] = bflo(pk.x); res[1] = bfhi(pk.x);
            res[2] = bflo(pk.y); res[3] = bfhi(pk.y);
            res[4] = bflo(pk.z); res[5] = bfhi(pk.z);
            res[6] = bflo(pk.w); res[7] = bfhi(pk.w);
        }
        int d0 = dg * 8;
        float* orow = h2 + (size_t)n * D2;
        if (dg < 2) {
#pragma unroll
            for (int j = 0; j < 8; j++) res[j] = fmaxf(res[j] + b2[d0 + j], 0.f);
            *reinterpret_cast<float4*>(orow + d0) = make_float4(res[0], res[1], res[2], res[3]);
            *reinterpret_cast<float4*>(orow + d0 + 4) = make_float4(res[4], res[5], res[6], res[7]);
        } else {
#pragma unroll
            for (int j = 0; j < 4; j++) res[j] = fmaxf(res[j] + b2[d0 + j], 0.f);
            *reinterpret_cast<float4*>(orow + d0) = make_float4(res[0], res[1], res[2], res[3]);
        }
    }
}

// ---------------- K7: pooling + gate + MLP, one block per graph ----------------
__global__ __launch_bounds__(256) void k_pool(const float* __restrict__ h2,
        const int* __restrict__ graph_start, const float* __restrict__ self_feat,
        const float* __restrict__ Wp, const float* __restrict__ bp,
        const float* __restrict__ Wf1, const float* __restrict__ bf1,
        const float* __restrict__ Wf2, const float* __restrict__ bf2,
        float* __restrict__ out) {
    __shared__ float red[8][D2];
    __shared__ float fbuf[D2];
    __shared__ float rbuf[10];
    int g = blockIdx.x;
    int start = graph_start[g], end = graph_start[g + 1];
    int tid = threadIdx.x;
    int j = tid & 31;
    int rs = tid >> 5;
    float a = 0.f;
    if (j < D2)
        for (int i = start + rs; i < end; i += 8) a += h2[(size_t)i * D2 + j];
    if (j < D2) red[rs][j] = a;
    __syncthreads();
    if (tid < D2) {
        float sum = 0.f;
#pragma unroll
        for (int k = 0; k < 8; k++) sum += red[k][tid];
        float m = (float)(end - start);
        float hg = sum / fmaxf(m, 1.f);
        float z = bp[tid];
        const float* sf = self_feat + g * DSELF;
        for (int k = 0; k < DSELF; k++) z += sf[k] * Wp[k * D2 + tid];
        float gate = 1.f / (1.f + expf(-hg * z));
        fbuf[tid] = gate * hg + (1.f - gate) * z;
    }
    __syncthreads();
    if (tid < 10) {
        float a2 = bf1[tid];
        for (int k = 0; k < D2; k++) a2 += fbuf[k] * Wf1[k * 10 + tid];
        rbuf[tid] = fmaxf(a2, 0.f);
    }
    __syncthreads();
    if (tid == 0) {
        float o = bf2[0];
        for (int k = 0; k < 10; k++) o += rbuf[k] * Wf2[k];
        out[g] = o;
    }
}

// ---------------- launch ----------------

extern "C" void kernel_launch(void* const* d_in, const int* in_sizes, int n_in,
                              void* d_out, int out_size, void* d_ws, size_t ws_size,
                              hipStream_t stream) {
    const float* feat      = (const float*)d_in[0];
    const int*   src       = (const int*)d_in[1];
    const int*   dst       = (const int*)d_in[2];
    const int*   gid       = (const int*)d_in[3];
    const float* self_feat = (const float*)d_in[4];
    const float* W1  = (const float*)d_in[5];
    const float* b1  = (const float*)d_in[6];
    const float* W2  = (const float*)d_in[7];
    const float* b2  = (const float*)d_in[8];
    const float* Wp  = (const float*)d_in[9];
    const float* bp  = (const float*)d_in[10];
    const float* Wf1 = (const float*)d_in[11];
    const float* bf1 = (const float*)d_in[12];
    const float* Wf2 = (const float*)d_in[13];
    const float* bf2 = (const float*)d_in[14];
    float* out = (float*)d_out;

    char* ws = (char*)d_ws;
    // Region A [0, 11,200,016): CSR-build scratch; y1bf aliases it after k_merge.
    int*            deg         = (int*)(ws + 0);          // 400000 ints
    int*            cursor      = (int*)(ws + 1600000);    // 400000 ints
    int*            row_start   = (int*)(ws + 3200000);    // 400001 ints -> 4800004, pad 4800016
    int*            csr         = (int*)(ws + 4800016);    // 1.6M ints -> 11200016
    unsigned short* y1bf        = (unsigned short*)(ws + 0); // 50001*104 bf16 = 10400208 (alias A)
    // Region B (persistent)
    int*            graph_start = (int*)(ws + 11200016);   // 257 ints -> pad 11201056
    int*            blksum      = (int*)(ws + 11201056);   // 98 ints
    int*            blkoff      = (int*)(ws + 11201568);   // 98 ints -> pad 11202080
    int*            mdeg        = (int*)(ws + 11202080);   // 50000 ints -> 11402080
    int*            mcsr        = (int*)(ws + 11402080);   // 50000*128 ints -> 37002080
    unsigned short* y2b         = (unsigned short*)(ws + 37002080); // 50001*24 bf16 -> 39402128, pad 39402144
    float*          h2          = (float*)(ws + 39402144); // 50000*20 fp32 -> 43402144

    hipMemsetAsync(deg, 0, 3200000, stream);   // deg + cursor (contiguous)

    k_deg_mark<<<DEG_BLOCKS + 196, 256, 0, stream>>>(dst, deg, gid, graph_start);
    k_scan1<<<SCAN_BLOCKS, 1024, 0, stream>>>(deg, row_start, blksum);
    k_scan2<<<1, 128, 0, stream>>>(blksum, blkoff, row_start);
    k_scan3<<<SCAN_BLOCKS, 1024, 0, stream>>>(row_start, blkoff);
    k_fill<<<DEG_BLOCKS, 256, 0, stream>>>(src, dst, row_start, cursor, csr);
    k_merge<<<12500, 256, 0, stream>>>(csr, row_start, mcsr, mdeg);
    // Region A scratch now dead; y1bf may overwrite it.
    k_gemm1<<<1250, 256, 0, stream>>>(feat, W1, y1bf, y2b);
    k_agg1g2<<<12500, 256, 0, stream>>>(y1bf, mcsr, mdeg, b1, W2, y2b);
    k_agg2<<<12500, 256, 0, stream>>>(y2b, mcsr, mdeg, b2, h2);
    k_pool<<<NG, 256, 0, stream>>>(h2, graph_start, self_feat, Wp, bp, Wf1, bf1, Wf2, bf2, out);
}